// Round 7
// baseline (3183.912 us; speedup 1.0000x reference)
//
#include <hip/hip_runtime.h>

#define B_ROWS 131072
#define NSTEP  65
#define ROWS   128                  // rows per block
#define NBLK   (B_ROWS / ROWS)      // 1024 blocks -> 2 blocks/CU, exactly 2 rounds

typedef __attribute__((ext_vector_type(8))) short short8;
typedef __attribute__((ext_vector_type(4))) float floatx4;
typedef __attribute__((ext_vector_type(4))) unsigned int uintx4;

__device__ __forceinline__ unsigned short f2bf(float f) {
    unsigned int u = __builtin_bit_cast(unsigned int, f);
    u += 0x7FFFu + ((u >> 16) & 1u);   // RNE; inputs are finite
    return (unsigned short)(u >> 16);
}
__device__ __forceinline__ float bf2f(unsigned short h) {
    unsigned int u = ((unsigned int)h) << 16;
    return __builtin_bit_cast(float, u);
}
__device__ __forceinline__ unsigned pk2bf(float a, float b) {
    return (unsigned)f2bf(a) | ((unsigned)f2bf(b) << 16);
}

// ---- pack W1 (65,63,256) fp32 -> bf16 frag order [stp][kc<2][n<256][32 k], k=63 zero-padded
__global__ __launch_bounds__(256) void pack_w1(const float* __restrict__ W1,
                                               unsigned short* __restrict__ out) {
    int t = blockIdx.x * 256 + threadIdx.x;            // 65*2*256 = 33280 threads
    int n = t & 255, kc = (t >> 8) & 1, stp = t >> 9;
    unsigned int wbuf[16];
#pragma unroll
    for (int e = 0; e < 16; ++e) {
        int k0 = kc * 32 + e * 2, k1 = k0 + 1;
        float v0 = (k0 < 63) ? W1[((size_t)stp * 63 + k0) * 256 + n] : 0.f;
        float v1 = (k1 < 63) ? W1[((size_t)stp * 63 + k1) * 256 + n] : 0.f;
        wbuf[e] = (unsigned)f2bf(v0) | ((unsigned)f2bf(v1) << 16);
    }
    uintx4* o = (uintx4*)out;
#pragma unroll
    for (int j = 0; j < 4; ++j) {
        uintx4 u = {wbuf[j*4+0], wbuf[j*4+1], wbuf[j*4+2], wbuf[j*4+3]};
        o[(size_t)t * 4 + j] = u;
    }
}

// ---- pack W2 (65,256,256) fp32 -> bf16 frag order [stp][kc<8][n<256][32 k]
__global__ __launch_bounds__(256) void pack_w2(const float* __restrict__ W2,
                                               unsigned short* __restrict__ out) {
    int t = blockIdx.x * 256 + threadIdx.x;            // 65*8*256 = 133120 threads
    int n = t & 255, kc = (t >> 8) & 7, stp = t >> 11;
    unsigned int wbuf[16];
#pragma unroll
    for (int e = 0; e < 16; ++e) {
        int k0 = kc * 32 + e * 2;
        float v0 = W2[((size_t)stp * 256 + k0) * 256 + n];
        float v1 = W2[((size_t)stp * 256 + k0 + 1) * 256 + n];
        wbuf[e] = (unsigned)f2bf(v0) | ((unsigned)f2bf(v1) << 16);
    }
    uintx4* o = (uintx4*)out;
#pragma unroll
    for (int j = 0; j < 4; ++j) {
        uintx4 u = {wbuf[j*4+0], wbuf[j*4+1], wbuf[j*4+2], wbuf[j*4+3]};
        o[(size_t)t * 4 + j] = u;
    }
}

// ---- whole 65-step flow. Block owns 128 rows. z master = bf16 frag-packed GLOBAL
// scratch zP (linear slot = row*64 + k; chunk layout == B-frag order). LDS only holds
// H1 (64 KB) + TR (2 KB) -> 2 blocks/CU. z63 lives in a register of its updater lane
// (slot 63 is never read: W1 k=63 is zero-padded), so the step-63 update propagates
// the NEW z63 by construction. Transposed-MFMA: A = weights, B = activations.
// C-layout: lane holds col1 = i4*16+q*4+r, row = j*16+c (j<8).
__global__ __launch_bounds__(256, 2) void flow_kernel(
    const float* __restrict__ x,
    const float* __restrict__ sg,
    unsigned short* __restrict__ zP,
    const unsigned short* __restrict__ Wb1p,
    const unsigned short* __restrict__ Wb2p,
    const float* __restrict__ b1g,
    const float* __restrict__ b2g,
    const float* __restrict__ w3g,
    const float* __restrict__ b3g,
    const int* __restrict__ idxg,
    float* __restrict__ out)
{
    __shared__ uintx4 H1[ROWS * 32];   // bf16 h1, swizzled                 65,536 B
    __shared__ float  TRf[512];        // [w*128+row] partials; reused       2,048 B

    const int tid  = threadIdx.x;
    const int w    = tid >> 6;         // wave 0..3 owns cols [w*64, w*64+64)
    const int lane = tid & 63;
    const int q    = lane >> 4;
    const int c    = lane & 15;
    const int b0   = blockIdx.x * ROWS;

    unsigned short* zS = zP + (size_t)blockIdx.x * (ROWS * 64);
    const uintx4*   zB = (const uintx4*)zS;
    unsigned long long* H1u = (unsigned long long*)H1;
    const uintx4* w1v = (const uintx4*)Wb1p;
    const uintx4* w2v = (const uintx4*)Wb2p;

    // ---- pack x -> zP (bf16); linear slot index == row*64 + k
#pragma unroll
    for (int it = 0; it < 4; ++it) {
        int cid = it * 256 + tid;              // 1024 chunks of 8 elems
        int row = cid >> 3, ch = cid & 7;
        const float4* xv = (const float4*)(x + (size_t)(b0 + row) * 64 + ch * 8);
        float4 a = xv[0], b = xv[1];
        uintx4 u;
        u.x = pk2bf(a.x, a.y); u.y = pk2bf(a.z, a.w);
        u.z = pk2bf(b.x, b.y); u.w = pk2bf(b.z, b.w);
        ((uintx4*)zS)[cid] = u;
    }
    __syncthreads();

    // ---- prologue (updater lane = row = tid < 128): z63 register + step-0 fixup
    float savedf = 0.f;
    unsigned short z63r = 0;
    int i_cur = idxg[0];
    if (tid < ROWS) {
        int row = tid;
        z63r = f2bf(x[(size_t)(b0 + row) * 64 + 63]);
        unsigned short old = zS[row * 64 + i_cur];
        savedf = (i_cur == 63) ? bf2f(z63r) : bf2f(old);
        zS[row * 64 + i_cur] = z63r;
    }
    __syncthreads();

#pragma unroll 1
    for (int step = 0; step < NSTEP; ++step) {
        const int i      = i_cur;
        const int i_next = (step + 1 < NSTEP) ? idxg[step + 1] : 0;
        const float b3v  = b3g[step];

        floatx4 acc[4][8];
#pragma unroll
        for (int a = 0; a < 4; ++a)
#pragma unroll
            for (int b = 0; b < 8; ++b) acc[a][b] = (floatx4){0.f, 0.f, 0.f, 0.f};

        // ---- phase 1: h1^T = W1^T @ z^T  (K=64; slot63 * 0-pad -> ignored)
#pragma unroll
        for (int kc = 0; kc < 2; ++kc) {
            short8 bz[8], aw[4];
#pragma unroll
            for (int j = 0; j < 8; ++j)
                bz[j] = __builtin_bit_cast(short8, zB[(j * 16 + c) * 8 + kc * 4 + q]);
#pragma unroll
            for (int i4 = 0; i4 < 4; ++i4)
                aw[i4] = __builtin_bit_cast(short8,
                    w1v[((size_t)(step * 2 + kc) * 256 + w * 64 + i4 * 16 + c) * 4 + q]);
#pragma unroll
            for (int i4 = 0; i4 < 4; ++i4)
#pragma unroll
                for (int j = 0; j < 8; ++j)
                    acc[i4][j] = __builtin_amdgcn_mfma_f32_16x16x32_bf16(
                        aw[i4], bz[j], acc[i4][j], 0, 0, 0);
        }

        // ---- epi-1: bias+relu -> H1 bf16 (4 consecutive cols per b64 store, swizzled)
#pragma unroll
        for (int i4 = 0; i4 < 4; ++i4) {
            int cb = step * 256 + w * 64 + i4 * 16 + q * 4;
            float4 bb = *(const float4*)(b1g + cb);
            int c16 = w * 8 + i4 * 2 + (q >> 1);
#pragma unroll
            for (int j = 0; j < 8; ++j) {
                int row = j * 16 + c;
                float h0 = fmaxf(acc[i4][j][0] + bb.x, 0.f);
                float h1 = fmaxf(acc[i4][j][1] + bb.y, 0.f);
                float h2 = fmaxf(acc[i4][j][2] + bb.z, 0.f);
                float h3 = fmaxf(acc[i4][j][3] + bb.w, 0.f);
                unsigned d0 = pk2bf(h0, h1);
                unsigned d1 = pk2bf(h2, h3);
                H1u[(row * 32 + (c16 ^ c)) * 2 + (q & 1)] =
                    (unsigned long long)d0 | ((unsigned long long)d1 << 32);
            }
        }
        __syncthreads();

        // ---- phase 2: h2^T = W2^T @ h1^T  (K=256)
#pragma unroll
        for (int a = 0; a < 4; ++a)
#pragma unroll
            for (int b = 0; b < 8; ++b) acc[a][b] = (floatx4){0.f, 0.f, 0.f, 0.f};

#pragma unroll
        for (int kc = 0; kc < 8; ++kc) {
            short8 bh[8], aw[4];
#pragma unroll
            for (int j = 0; j < 8; ++j)
                bh[j] = __builtin_bit_cast(short8,
                    H1[(j * 16 + c) * 32 + ((kc * 4 + q) ^ c)]);
#pragma unroll
            for (int i4 = 0; i4 < 4; ++i4)
                aw[i4] = __builtin_bit_cast(short8,
                    w2v[((size_t)(step * 8 + kc) * 256 + w * 64 + i4 * 16 + c) * 4 + q]);
#pragma unroll
            for (int i4 = 0; i4 < 4; ++i4)
#pragma unroll
                for (int j = 0; j < 8; ++j)
                    acc[i4][j] = __builtin_amdgcn_mfma_f32_16x16x32_bf16(
                        aw[i4], bh[j], acc[i4][j], 0, 0, 0);
        }

        // ---- epi-2: t = relu(h2 + b2) . w3 (16 cols in-register; 2 shuffles)
        {
            float p[8];
#pragma unroll
            for (int j = 0; j < 8; ++j) p[j] = 0.f;
#pragma unroll
            for (int i4 = 0; i4 < 4; ++i4) {
                int cb = step * 256 + w * 64 + i4 * 16 + q * 4;
                float4 bb = *(const float4*)(b2g + cb);
                float4 ww = *(const float4*)(w3g + cb);
#pragma unroll
                for (int j = 0; j < 8; ++j) {
                    p[j] += fmaxf(acc[i4][j][0] + bb.x, 0.f) * ww.x;
                    p[j] += fmaxf(acc[i4][j][1] + bb.y, 0.f) * ww.y;
                    p[j] += fmaxf(acc[i4][j][2] + bb.z, 0.f) * ww.z;
                    p[j] += fmaxf(acc[i4][j][3] + bb.w, 0.f) * ww.w;
                }
            }
#pragma unroll
            for (int j = 0; j < 8; ++j) {
                float t = p[j];
                t += __shfl_xor(t, 16, 64);
                t += __shfl_xor(t, 32, 64);
                if (q == 0) TRf[w * 128 + j * 16 + c] = t;
            }
        }
        __syncthreads();

        // ---- update (tid<128): z[row][i] = saved + t; carry z63 in reg; fixup i_next
        if (tid < ROWS) {
            int row = tid;
            float t = TRf[row] + TRf[128 + row] + TRf[256 + row] + TRf[384 + row] + b3v;
            float nz = savedf + t;
            unsigned short nzb = f2bf(nz);
            if (i == 63) z63r = nzb;          // step 63: col-63 itself updated
            zS[row * 64 + i] = nzb;
            if (step + 1 < NSTEP) {
                unsigned short old = zS[row * 64 + i_next];
                savedf = (i_next == 63) ? bf2f(z63r) : bf2f(old);
                zS[row * 64 + i_next] = z63r; // slot i_next shows z63 for next step
            }
        }
        i_cur = i_next;
        __syncthreads();
    }

    // ---- finalize: out[b][j] = exp(s[j]) * z  (col 63 from z63 registers)
    if (tid < 64) TRf[tid] = expf(sg[tid]);
    if (tid < ROWS) TRf[128 + tid] = bf2f(z63r);
    __syncthreads();
#pragma unroll
    for (int it = 0; it < 4; ++it) {
        int cid = it * 256 + tid;
        int row = cid >> 3, ch = cid & 7;
        uintx4 u = ((const uintx4*)zS)[cid];
        float v[8];
        v[0] = bf2f((unsigned short)(u.x & 0xFFFF)); v[1] = bf2f((unsigned short)(u.x >> 16));
        v[2] = bf2f((unsigned short)(u.y & 0xFFFF)); v[3] = bf2f((unsigned short)(u.y >> 16));
        v[4] = bf2f((unsigned short)(u.z & 0xFFFF)); v[5] = bf2f((unsigned short)(u.z >> 16));
        v[6] = bf2f((unsigned short)(u.w & 0xFFFF)); v[7] = bf2f((unsigned short)(u.w >> 16));
        if (ch == 7) v[7] = TRf[128 + row];   // true z63 (slot 63 is scratch)
        float4 o0, o1;
        o0.x = v[0] * TRf[ch * 8 + 0]; o0.y = v[1] * TRf[ch * 8 + 1];
        o0.z = v[2] * TRf[ch * 8 + 2]; o0.w = v[3] * TRf[ch * 8 + 3];
        o1.x = v[4] * TRf[ch * 8 + 4]; o1.y = v[5] * TRf[ch * 8 + 5];
        o1.z = v[6] * TRf[ch * 8 + 6]; o1.w = v[7] * TRf[ch * 8 + 7];
        float4* ov = (float4*)(out + (size_t)(b0 + row) * 64 + ch * 8);
        ov[0] = o0; ov[1] = o1;
    }
}

extern "C" void kernel_launch(void* const* d_in, const int* in_sizes, int n_in,
                              void* d_out, int out_size, void* d_ws, size_t ws_size,
                              hipStream_t stream) {
    const float* x  = (const float*)d_in[0];
    const float* s  = (const float*)d_in[1];
    const float* W1 = (const float*)d_in[2];
    const float* b1 = (const float*)d_in[3];
    const float* W2 = (const float*)d_in[4];
    const float* b2 = (const float*)d_in[5];
    const float* W3 = (const float*)d_in[6];
    const float* b3 = (const float*)d_in[7];
    const int* idx  = (const int*)d_in[8];
    float* out = (float*)d_out;

    char* ws = (char*)d_ws;
    const size_t ZP_BYTES  = (size_t)B_ROWS * 64 * 2;            // 16,777,216
    const size_t W1P_BYTES = (size_t)NSTEP * 2 * 256 * 32 * 2;   //  2,129,920
    unsigned short* zP   = (unsigned short*)ws;
    unsigned short* Wb1p = (unsigned short*)(ws + ZP_BYTES);
    unsigned short* Wb2p = (unsigned short*)(ws + ZP_BYTES + W1P_BYTES);

    pack_w1<<<130, 256, 0, stream>>>(W1, Wb1p);
    pack_w2<<<520, 256, 0, stream>>>(W2, Wb2p);
    flow_kernel<<<NBLK, 256, 0, stream>>>(x, s, zP, Wb1p, Wb2p, b1, b2, W3, b3, idx, out);
}